// Round 5
// baseline (88.511 us; speedup 1.0000x reference)
//
#include <hip/hip_runtime.h>
#include <math.h>

#define KTOP 200
#define NPART 32
#define BLOCK 512
#define NHIST 2048
#define HOFF 2049          // replica-1 offset: shifts banks by +1
#define CAND_CAP 1024
#define WCAP 512
#define MAXIT 10           // cached trips cover nfus <= 4*BLOCK*MAXIT = 20480

// d2 exactly as numpy: ((dx*dx + dy*dy) + dz*dz), no fma contraction
__device__ __forceinline__ float d2_ref(float ax, float ay, float az,
                                        float bx, float by, float bz) {
    float dx = __fsub_rn(ax, bx), dy = __fsub_rn(ay, by), dz = __fsub_rn(az, bz);
    return __fadd_rn(__fadd_rn(__fmul_rn(dx, dx), __fmul_rn(dy, dy)), __fmul_rn(dz, dz));
}

__device__ __forceinline__ unsigned key_of(const float* __restrict__ fus, int j,
                                           float vx, float vy, float vz) {
    return __float_as_uint(d2_ref(vx, vy, vz, fus[3*j], fus[3*j+1], fus[3*j+2]));
}

// shape-context bin of rel = p_j - q0, mirroring the reference f32 math
__device__ __forceinline__ int compute_bin(float rx, float ry, float rz) {
    const float TWO_PI_F = (float)6.283185307179586;
    const float PI_F     = (float)3.141592653589793;
    const float XY_W     = (float)(6.283185307179586 / 4.0);
    const float ZY_W     = (float)(3.141592653589793 / 4.0);

    float d2 = __fadd_rn(__fadd_rn(__fmul_rn(rx, rx), __fmul_rn(ry, ry)), __fmul_rn(rz, rz));
    float D  = sqrtf(__fadd_rn(d2, 1e-7f));
    float dist_bin;
    if (D >= 4.0f)      dist_bin = 1.0f;
    else if (D >= 1.0f) dist_bin = 0.0f;
    else                return -1;

    float axy = fmodf(atan2f(ry, rx) + TWO_PI_F, TWO_PI_F);
    float azy = fmodf(atan2f(ry, rz) + TWO_PI_F, PI_F);
    float xyb = floorf(__fdiv_rn(axy, XY_W));
    float zyb = floorf(__fdiv_rn(azy, ZY_W));
    if (!(xyb >= 0.0f && zyb >= 0.0f)) return -1;
    float ab  = xyb * 4.0f + zyb;
    int bin = (int)(dist_bin * 16.0f + ab);
    return bin;
}

__global__ __launch_bounds__(BLOCK, 8)
void shape_context_kernel(const float* __restrict__ veh,
                          const float* __restrict__ fus,
                          float* __restrict__ out,
                          int nfus) {
    const int b   = blockIdx.x;
    const int tid = threadIdx.x;
    const int lane = tid & 63;
    const int wid  = tid >> 6;

    __shared__ unsigned int hist[2 * NHIST + 1];          // two bank-shifted replicas
    __shared__ unsigned long long cand[CAND_CAP];
    __shared__ int wlist[WCAP];
    __shared__ unsigned int hist32[NPART];
    __shared__ unsigned int waveTot[BLOCK / 64];
    __shared__ unsigned int waveBase[BLOCK / 64];
    __shared__ unsigned int s_bucket, s_rem, s_bcount, s_b0;
    __shared__ int s_candCount, s_wcount;
    __shared__ unsigned long long s_minPacked, s_lowBound;

    const float vx = veh[b * 3 + 0], vy = veh[b * 3 + 1], vz = veh[b * 3 + 2];
    const float4* fus4 = (const float4*)fus;
    const int ntrip = nfus >> 2;
    const int hoff = (lane & 32) ? HOFF : 0;   // per-half-wave replica

    if (tid == 0) { s_minPacked = ~0ull; s_candCount = 0; s_wcount = 0; }
    for (int i = tid; i < 2 * NHIST + 1; i += BLOCK) hist[i] = 0;
    if (tid < NPART) hist32[tid] = 0;
    __syncthreads();

    // block-wide: find bucket where cumulative count crosses remq; also first nonzero bucket (s_b0)
    auto find_bucket = [&](unsigned remq) {
        const int PER = NHIST / BLOCK;  // 4
        int base = tid * PER;
        unsigned c[PER];
        unsigned p = 0;
        #pragma unroll
        for (int i = 0; i < PER; i++) { c[i] = hist[base + i] + hist[HOFF + base + i]; p += c[i]; }
        unsigned incl = p;
        #pragma unroll
        for (int d = 1; d < 64; d <<= 1) {
            unsigned n = __shfl_up(incl, d, 64);
            if (lane >= d) incl += n;
        }
        if (lane == 63) waveTot[wid] = incl;
        __syncthreads();
        if (tid == 0) {
            unsigned acc = 0;
            for (int w = 0; w < BLOCK / 64; w++) { waveBase[w] = acc; acc += waveTot[w]; }
        }
        __syncthreads();
        unsigned excl = waveBase[wid] + incl - p;
        if (excl == 0 && p > 0) {               // first nonzero bucket (unique thread)
            #pragma unroll
            for (int i = 0; i < PER; i++) if (c[i] > 0) { s_b0 = base + i; break; }
        }
        if (excl < remq && remq <= excl + p) {  // crossing thread (unique)
            unsigned cum = excl;
            #pragma unroll
            for (int i = 0; i < PER; i++) {
                if (cum + c[i] >= remq) { s_bucket = base + i; s_rem = remq - cum; s_bcount = c[i]; break; }
                cum += c[i];
            }
        }
        __syncthreads();
    };

    // ---- scan A: keys -> replicated coarse hist (key>>21); cache 4x16-bit bucket ids ----
    unsigned long long khi[MAXIT];
    #pragma unroll
    for (int it = 0; it < MAXIT; ++it) {
        int m = tid + it * BLOCK;
        if (m < ntrip) {
            float4 A = fus4[3 * m], Bq = fus4[3 * m + 1], Cq = fus4[3 * m + 2];
            unsigned k0 = __float_as_uint(d2_ref(vx, vy, vz, A.x,  A.y,  A.z));
            unsigned k1 = __float_as_uint(d2_ref(vx, vy, vz, A.w,  Bq.x, Bq.y));
            unsigned k2 = __float_as_uint(d2_ref(vx, vy, vz, Bq.z, Bq.w, Cq.x));
            unsigned k3 = __float_as_uint(d2_ref(vx, vy, vz, Cq.y, Cq.z, Cq.w));
            atomicAdd(&hist[hoff + (k0 >> 21)], 1u);
            atomicAdd(&hist[hoff + (k1 >> 21)], 1u);
            atomicAdd(&hist[hoff + (k2 >> 21)], 1u);
            atomicAdd(&hist[hoff + (k3 >> 21)], 1u);
            khi[it] = (unsigned long long)(k0 >> 21)
                    | ((unsigned long long)(k1 >> 21) << 16)
                    | ((unsigned long long)(k2 >> 21) << 32)
                    | ((unsigned long long)(k3 >> 21) << 48);
        } else {
            khi[it] = 0xFFFFFFFFFFFFFFFFull;   // sentinel: 0xFFFF fields never match
        }
    }
    // streaming extras (nfus > 20480 or nfus % 4 != 0) — not cached
    for (int m = MAXIT * BLOCK + tid; m < ntrip; m += BLOCK)
        #pragma unroll
        for (int q = 0; q < 4; ++q)
            atomicAdd(&hist[hoff + (key_of(fus, 4 * m + q, vx, vy, vz) >> 21)], 1u);
    for (int j = (nfus & ~3) + tid; j < nfus; j += BLOCK)
        atomicAdd(&hist[hoff + (key_of(fus, j, vx, vy, vz) >> 21)], 1u);
    __syncthreads();

    find_bucket(KTOP);
    unsigned T = s_bucket;
    unsigned rem = s_rem;
    unsigned bcount = s_bcount;
    const unsigned b0 = s_b0;
    int shift = 21;

    // ---- stable argmin: exact (key,idx) min among the few points in bucket b0 ----
    #pragma unroll
    for (int it = 0; it < MAXIT; ++it) {
        unsigned long long packed = khi[it];
        int jb = 4 * (tid + it * BLOCK);
        #pragma unroll
        for (int q = 0; q < 4; ++q) {
            unsigned hi = (unsigned)((packed >> (16 * q)) & 0xFFFFull);
            if (hi == b0) {
                int j = jb + q;
                unsigned k = key_of(fus, j, vx, vy, vz);
                atomicMin(&s_minPacked, ((unsigned long long)k << 32) | (unsigned)j);
            }
        }
    }
    for (int m = MAXIT * BLOCK + tid; m < ntrip; m += BLOCK)
        #pragma unroll
        for (int q = 0; q < 4; ++q) {
            unsigned k = key_of(fus, 4 * m + q, vx, vy, vz);
            if ((k >> 21) == b0) atomicMin(&s_minPacked, ((unsigned long long)k << 32) | (unsigned)(4 * m + q));
        }
    for (int j = (nfus & ~3) + tid; j < nfus; j += BLOCK) {
        unsigned k = key_of(fus, j, vx, vy, vz);
        if ((k >> 21) == b0) atomicMin(&s_minPacked, ((unsigned long long)k << 32) | (unsigned)j);
    }

    // ---- rare: refine threshold bucket if too many candidates (reload-based) ----
    while (bcount > CAND_CAP && shift > 0) {
        int newshift = (shift > 11) ? (shift - 11) : 0;
        unsigned digmask = (1u << (shift - newshift)) - 1;
        __syncthreads();
        for (int i = tid; i < 2 * NHIST + 1; i += BLOCK) hist[i] = 0;
        __syncthreads();
        for (int j = tid; j < nfus; j += BLOCK) {
            unsigned k = key_of(fus, j, vx, vy, vz);
            if ((k >> shift) == T) atomicAdd(&hist[hoff + ((k >> newshift) & digmask)], 1u);
        }
        __syncthreads();
        find_bucket(rem);
        T = (T << (shift - newshift)) | s_bucket;
        rem = s_rem;
        bcount = s_bcount;
        shift = newshift;
    }

    // ---- scan B: winners -> wlist, boundary bucket -> cand (exact keys via reload) ----
    if (shift == 21) {
        #pragma unroll
        for (int it = 0; it < MAXIT; ++it) {
            unsigned long long packed = khi[it];
            int jb = 4 * (tid + it * BLOCK);
            #pragma unroll
            for (int q = 0; q < 4; ++q) {
                unsigned hi = (unsigned)((packed >> (16 * q)) & 0xFFFFull);
                if (hi < T) {
                    int pos = atomicAdd(&s_wcount, 1);
                    if (pos < WCAP) wlist[pos] = jb + q;
                } else if (hi == T) {
                    int j = jb + q;
                    unsigned k = key_of(fus, j, vx, vy, vz);
                    int pos = atomicAdd(&s_candCount, 1);
                    if (pos < CAND_CAP) cand[pos] = ((unsigned long long)k << 32) | (unsigned)j;
                }
            }
        }
        for (int m = MAXIT * BLOCK + tid; m < ntrip; m += BLOCK)
            #pragma unroll
            for (int q = 0; q < 4; ++q) {
                int j = 4 * m + q;
                unsigned k = key_of(fus, j, vx, vy, vz);
                unsigned hi = k >> shift;
                if (hi < T) { int pos = atomicAdd(&s_wcount, 1); if (pos < WCAP) wlist[pos] = j; }
                else if (hi == T) { int pos = atomicAdd(&s_candCount, 1); if (pos < CAND_CAP) cand[pos] = ((unsigned long long)k << 32) | (unsigned)j; }
            }
        for (int j = (nfus & ~3) + tid; j < nfus; j += BLOCK) {
            unsigned k = key_of(fus, j, vx, vy, vz);
            unsigned hi = k >> shift;
            if (hi < T) { int pos = atomicAdd(&s_wcount, 1); if (pos < WCAP) wlist[pos] = j; }
            else if (hi == T) { int pos = atomicAdd(&s_candCount, 1); if (pos < CAND_CAP) cand[pos] = ((unsigned long long)k << 32) | (unsigned)j; }
        }
    } else {
        for (int j = tid; j < nfus; j += BLOCK) {
            unsigned k = key_of(fus, j, vx, vy, vz);
            unsigned hi = k >> shift;
            if (hi < T) { int pos = atomicAdd(&s_wcount, 1); if (pos < WCAP) wlist[pos] = j; }
            else if (hi == T) { int pos = atomicAdd(&s_candCount, 1); if (pos < CAND_CAP) cand[pos] = ((unsigned long long)k << 32) | (unsigned)j; }
        }
    }
    __syncthreads();   // also guarantees s_minPacked is final

    const int cnt = s_candCount;
    if (cnt <= CAND_CAP) {
        // exact stable ranking among boundary candidates by (key, idx); qualifiers join wlist
        for (int i = tid; i < cnt; i += BLOCK) {
            unsigned long long me = cand[i];
            int rank = 0;
            for (int k2 = 0; k2 < cnt; k2++) rank += (cand[k2] < me) ? 1 : 0;
            if (rank < (int)rem) {
                int pos = atomicAdd(&s_wcount, 1);
                if (pos < WCAP) wlist[pos] = (int)(me & 0xFFFFFFFFull);
            }
        }
    }
    __syncthreads();

    // q0 = nearest point (stable): same-address loads broadcast from L1
    const int idx0 = (int)(s_minPacked & 0xFFFFFFFFull);
    const float q0x = fus[idx0 * 3], q0y = fus[idx0 * 3 + 1], q0z = fus[idx0 * 3 + 2];

    // ---- compact winner processing: ~one compute_bin per thread ----
    {
        int wc = s_wcount; if (wc > WCAP) wc = WCAP;
        for (int i = tid; i < wc; i += BLOCK) {
            int j = wlist[i];
            float fx = fus[3 * j], fy = fus[3 * j + 1], fz = fus[3 * j + 2];
            int bin = compute_bin(__fsub_rn(fx, q0x), __fsub_rn(fy, q0y), __fsub_rn(fz, q0z));
            if (bin >= 0 && bin < NPART) atomicAdd(&hist32[bin], 1u);
        }
    }

    if (cnt > CAND_CAP) {
        // pathological fallback: serial extraction of `rem` smallest packed (key,idx) in bucket T
        if (tid == 0) s_lowBound = 0;
        __syncthreads();
        for (unsigned itx = 0; itx < rem; ++itx) {
            if (tid == 0) s_minPacked = ~0ull;
            __syncthreads();
            unsigned long long lowB = s_lowBound;
            unsigned long long lm = ~0ull;
            for (int j = tid; j < nfus; j += BLOCK) {
                unsigned k = key_of(fus, j, vx, vy, vz);
                if ((k >> shift) == T) {
                    unsigned long long p = ((unsigned long long)k << 32) | (unsigned)j;
                    if (p >= lowB && p < lm) lm = p;
                }
            }
            #pragma unroll
            for (int d = 32; d > 0; d >>= 1) {
                unsigned long long o = __shfl_xor(lm, d, 64);
                lm = (o < lm) ? o : lm;
            }
            if (lane == 0) atomicMin(&s_minPacked, lm);
            __syncthreads();
            if (tid == 0) {
                int jm = (int)(s_minPacked & 0xFFFFFFFFull);
                float fx = fus[jm * 3], fy = fus[jm * 3 + 1], fz = fus[jm * 3 + 2];
                int bin = compute_bin(__fsub_rn(fx, q0x), __fsub_rn(fy, q0y), __fsub_rn(fz, q0z));
                if (bin >= 0 && bin < NPART) hist32[bin] += 1u;
                s_lowBound = s_minPacked + 1;
            }
            __syncthreads();
        }
    }
    __syncthreads();

    // ---- epilogue (32 lanes of wave 0): counts+1 -> L2-normalize*4 -> softmax ----
    if (tid < NPART) {
        float c = (float)hist32[tid] + 1.0f;
        float ss = __fmul_rn(c, c);
        #pragma unroll
        for (int d = 16; d > 0; d >>= 1) ss += __shfl_xor(ss, d, 64);
        float v = __fmul_rn(__fdiv_rn(c, sqrtf(ss)), 4.0f);
        float mx = v;
        #pragma unroll
        for (int d = 16; d > 0; d >>= 1) mx = fmaxf(mx, __shfl_xor(mx, d, 64));
        float e = expf(v - mx);
        float sum = e;
        #pragma unroll
        for (int d = 16; d > 0; d >>= 1) sum += __shfl_xor(sum, d, 64);
        out[b * NPART + tid] = __fdiv_rn(e, sum);
    }
}

extern "C" void kernel_launch(void* const* d_in, const int* in_sizes, int n_in,
                              void* d_out, int out_size, void* d_ws, size_t ws_size,
                              hipStream_t stream) {
    const float* veh = (const float*)d_in[0];   // (1024, 3)
    const float* fus = (const float*)d_in[1];   // (20000, 3)
    float* out = (float*)d_out;                 // (1024, 32)
    int nveh = in_sizes[0] / 3;
    int nfus = in_sizes[1] / 3;
    shape_context_kernel<<<nveh, BLOCK, 0, stream>>>(veh, fus, out, nfus);
}